// Round 5
// baseline (6377.885 us; speedup 1.0000x reference)
//
#include <hip/hip_runtime.h>
#include <hip/hip_bf16.h>

#define Bsz   1024
#define Lseq  50
#define Din   4
#define Hd    512
#define Tlen  30
#define NWG   256

typedef __hip_bfloat16 bf16;
typedef short s16x8 __attribute__((ext_vector_type(8)));
typedef short s16x4 __attribute__((ext_vector_type(4)));
typedef float f32x4 __attribute__((ext_vector_type(4)));

__device__ __forceinline__ float bf2f(bf16 x){ return __bfloat162float(x); }
__device__ __forceinline__ bf16  f2bf(float x){ return __float2bfloat16(x); }
__device__ __forceinline__ float bfbits2f(short u){
    union { unsigned int ui; float f; } v;
    v.ui = ((unsigned int)(unsigned short)u) << 16;
    return v.f;
}
__device__ __forceinline__ short f2bfbits(float x){
    bf16 h = f2bf(x); short s; __builtin_memcpy(&s, &h, 2); return s;
}
__device__ __forceinline__ float sigm(float x){ return 1.0f/(1.0f + __expf(-x)); }

// ---------------- ws layout (bytes) ----------------
#define OFF_ABUF0   (0u)
#define OFF_ABUF1   (2u<<20)
#define OFF_CBUF    (4u<<20)
#define OFF_HF32    (6u<<20)
#define OFF_ATTNAP  (8u<<20)
#define OFF_XDEC    (9u<<20)
#define OFF_FLAG    ((9u<<20) + (16u<<10))
#define OFF_CNT     ((9u<<20) + (20u<<10))
#define OFF_COMBWR  ((9u<<20) + (32u<<10))
#define OFF_ATTNWR  ((9u<<20) + (600u<<10))
#define OFF_WCACHE  (10u<<20)
#define OFF_ENCOUT  (18u<<20)

// wcache element offsets (bf16 elements), 8-elem aligned per array
#define WC_INPUT 0
#define WC_EWIH  204800
#define WC_EWHH  212992
#define WC_EBIH  1261568
#define WC_EBHH  1263616
#define WC_AW    1265664
#define WC_AB    1291464
#define WC_CW    1291520
#define WC_CB    1555712
#define WC_DWIH  1556224
#define WC_DWHH  2604800
#define WC_DBIH  3653376
#define WC_DBHH  3655424
#define WC_OW    3657472
#define WC_OB    3659520
#define WC_TOTAL 3659524

__device__ __constant__ int WOFF[15] = {
    WC_INPUT, WC_EWIH, WC_EWHH, WC_EBIH, WC_EBHH, WC_AW, WC_AB, WC_CW,
    WC_CB, WC_DWIH, WC_DWHH, WC_DBIH, WC_DBHH, WC_OW, WC_OB };
__device__ __constant__ int WNUM[15] = {
    204800, 8192, 1048576, 2048, 2048, 25800, 50, 264192,
    512, 1048576, 1048576, 2048, 2048, 2048, 4 };

struct Ptrs15 { const void* p[15]; };

// ---------------------------------------------------------------------------
// Dtype probe (bf16 vs fp32 inputs); flag=1 -> fp32.
// ---------------------------------------------------------------------------
__global__ void probe_kernel(const unsigned int* __restrict__ w, int* flag){
    __shared__ int cnt;
    if (threadIdx.x == 0) cnt = 0;
    __syncthreads();
    int c = 0;
    for (int i = threadIdx.x; i < 4096; i += 256){
        unsigned e = (w[i] >> 7) & 0xFFu;
        c += (e >= 0x80u) ? 1 : 0;
    }
    atomicAdd(&cnt, c);
    __syncthreads();
    if (threadIdx.x == 0) *flag = (cnt > 400) ? 1 : 0;
}

__global__ __launch_bounds__(256) void convert_kernel(
    Ptrs15 srcs, const int* __restrict__ flag, bf16* __restrict__ dst)
{
    const int f = *flag;
    for (int idx = blockIdx.x*256 + threadIdx.x; idx < WC_TOTAL;
         idx += gridDim.x*256){
        int a = 0;
#pragma unroll
        for (int j = 1; j < 15; ++j) if (idx >= WOFF[j]) a = j;
        const int local = idx - WOFF[a];
        if (local >= WNUM[a]) continue;
        bf16 v;
        if (f) v = f2bf(((const float*)srcs.p[a])[local]);
        else   v = ((const bf16*)srcs.p[a])[local];
        dst[idx] = v;
    }
}

__global__ __launch_bounds__(256) void setup_kernel(
    bf16* __restrict__ Abuf0, bf16* __restrict__ Abuf1,
    float* __restrict__ cbuf, bf16* __restrict__ combWr,
    bf16* __restrict__ attnWr,
    const bf16* __restrict__ cWc, const bf16* __restrict__ aWc)
{
    const unsigned idx = blockIdx.x*256u + threadIdx.x;
    if (idx < (unsigned)Bsz*Hd){
        const unsigned row = idx >> 9, col = idx & (Hd-1);
        const bf16 z = f2bf(0.0f);
        Abuf0[(size_t)row*1024 + Hd + col] = z;
        Abuf1[(size_t)row*1024 + Hd + col] = z;
        cbuf[idx] = 0.0f;
    }
    if (idx < (unsigned)Hd*Hd)
        combWr[idx] = cWc[(size_t)(idx >> 9)*(Hd+Din) + Din + (idx & (Hd-1))];
    if (idx < (unsigned)Lseq*Hd)
        attnWr[idx] = aWc[(size_t)(idx >> 9)*(Hd+Din) + Din + (idx & (Hd-1))];
}

// ---------------------------------------------------------------------------
// Device-scope grid barrier (all 256 WGs co-resident: 1 WG/CU guaranteed by
// 26KB LDS / <=256 VGPR / grid 256). Monotone counter in ws, zeroed per call.
// ---------------------------------------------------------------------------
__device__ __forceinline__ void gridbar(int* cnt, int target){
    __syncthreads();   // drains all waves' vmem before tid0 fences
    if (threadIdx.x == 0){
        __threadfence();  // agent release: L2 writeback -> visible cross-XCD
        __hip_atomic_fetch_add(cnt, 1, __ATOMIC_RELEASE, __HIP_MEMORY_SCOPE_AGENT);
        while (__hip_atomic_load(cnt, __ATOMIC_RELAXED, __HIP_MEMORY_SCOPE_AGENT) < target)
            __builtin_amdgcn_s_sleep(2);
        (void)__hip_atomic_load(cnt, __ATOMIC_ACQUIRE, __HIP_MEMORY_SCOPE_AGENT);
    }
    __syncthreads();
}

struct MegaP {
    const bf16 *input, *eWih, *eWhh, *ebih, *ebhh;
    const bf16 *aW, *ab, *cW, *cb, *dWih, *dWhh, *dbih, *dbhh, *oW, *ob;
    const bf16 *combWr, *attnWr;
    bf16 *A0, *A1, *encout, *attnap, *xdec;
    float *cbuf, *hf32;
    int *cnt;
    const int *flag;
    void *dout;
};

// ---------------------------------------------------------------------------
// Persistent megakernel: 50 enc LSTM steps + 30 dec (attn -> comb -> gates)
// with device-wide barriers. 256 WGs x 512 thr (8 waves), 1 WG/CU.
// Gates tiling: WG = 64m x 128n (nt: 32 hcols), wave = 32m x 32n.
// enc W (and dec W_ih half) held in 128 VGPRs/lane across all steps.
// ---------------------------------------------------------------------------
__global__ __launch_bounds__(512, 2) void mega_kernel(MegaP P)
{
    __shared__ float hr_s[4][Hd];        // 8 KB  (dec attn)
    __shared__ float ctx_s[2][4][Hd];    // 16 KB (dec context halves)
    __shared__ float aw_s[4][64];        // 1 KB  (softmax weights)

    const int wg = blockIdx.x, tid = threadIdx.x;
    const int wave = tid >> 6, lane = tid & 63;
    const int quad = lane >> 4, l15 = lane & 15;
    const int lbase = lane & ~3;
    const int f32out = *P.flag;
    int bar = 0;

    bf16* bufs[2] = { P.A0, P.A1 };

    // ---- gates tile decode (shared by enc and dec gates) ----
    const int mt = wg >> 4, nt = wg & 15;
    const int bm0 = mt << 6, hc0 = nt << 5;
    const int wm = wave >> 2, wn = wave & 3;     // 2 x 4 waves
    const int arow0 = bm0 + wm*32 + l15;

    int ng[2];
#pragma unroll
    for (int nf = 0; nf < 2; ++nf){
        const int n = wn*32 + nf*16 + l15;
        ng[nf] = (n & 3)*Hd + hc0 + (n >> 2);
    }

    // ================= ENCODER =================
    float bias_e[2], wxv_e[2][4];
#pragma unroll
    for (int nf = 0; nf < 2; ++nf){
        bias_e[nf] = bf2f(P.ebih[ng[nf]]) + bf2f(P.ebhh[ng[nf]]);
        const s16x4 t4 = *reinterpret_cast<const s16x4*>(P.eWih + (size_t)ng[nf]*Din);
#pragma unroll
        for (int d = 0; d < 4; ++d) wxv_e[nf][d] = bfbits2f(t4[d]);
    }

    // W_hh fragments resident in registers for all 50 steps (128 VGPR)
    s16x8 breg[2][16];
#pragma unroll
    for (int nf = 0; nf < 2; ++nf)
#pragma unroll
        for (int sl = 0; sl < 16; ++sl)
            breg[nf][sl] = *reinterpret_cast<const s16x8*>(
                P.eWhh + (size_t)ng[nf]*Hd + sl*32 + quad*8);

    for (int t = 0; t < Lseq; ++t){
        const bf16* Ain = bufs[t&1] + Hd;
        bf16* hout = bufs[(t+1)&1] + Hd;

        f32x4 acc[2][2];
#pragma unroll
        for (int mf=0; mf<2; ++mf)
#pragma unroll
            for (int nf=0; nf<2; ++nf) acc[mf][nf] = (f32x4)0.0f;

        s16x8 afr[2];
#pragma unroll
        for (int sl = 0; sl < 16; ++sl){
#pragma unroll
            for (int mf = 0; mf < 2; ++mf)
                afr[mf] = *reinterpret_cast<const s16x8*>(
                    Ain + (size_t)(arow0 + mf*16)*1024 + sl*32 + quad*8);
#pragma unroll
            for (int mf = 0; mf < 2; ++mf)
#pragma unroll
                for (int nf = 0; nf < 2; ++nf)
                    acc[mf][nf] = __builtin_amdgcn_mfma_f32_16x16x32_bf16(
                        afr[mf], breg[nf][sl], acc[mf][nf], 0, 0, 0);
        }

        // epilogue
#pragma unroll
        for (int mf = 0; mf < 2; ++mf){
#pragma unroll
            for (int r = 0; r < 4; ++r){
                const int m = bm0 + wm*32 + mf*16 + quad*4 + r;
                const s16x4 xt = *reinterpret_cast<const s16x4*>(
                    P.input + ((size_t)m*Lseq + t)*Din);
                float xv[4];
#pragma unroll
                for (int d = 0; d < 4; ++d) xv[d] = bfbits2f(xt[d]);
#pragma unroll
                for (int nf = 0; nf < 2; ++nf){
                    const int n_loc = wn*32 + nf*16 + l15;
                    float gv = acc[mf][nf][r] + bias_e[nf]
                             + xv[0]*wxv_e[nf][0] + xv[1]*wxv_e[nf][1]
                             + xv[2]*wxv_e[nf][2] + xv[3]*wxv_e[nf][3];
                    const float gi = __shfl(gv, lbase+0);
                    const float gf = __shfl(gv, lbase+1);
                    const float gg = __shfl(gv, lbase+2);
                    const float go = __shfl(gv, lbase+3);
                    if ((lane & 3) == 0){
                        const int hcol = hc0 + (n_loc >> 2);
                        const size_t ci = (size_t)m*Hd + hcol;
                        const float cn = sigm(gf)*P.cbuf[ci] + sigm(gi)*tanhf(gg);
                        P.cbuf[ci] = cn;
                        const float hv = sigm(go)*tanhf(cn);
                        hout[(size_t)m*1024 + hcol] = f2bf(hv);
                        P.hf32[ci] = hv;
                        P.encout[((size_t)m*Lseq + t)*Hd + hcol] = f2bf(hv);
                    }
                }
            }
        }
        gridbar(P.cnt, (++bar)*NWG);
    }

    // ================= DECODER =================
    // reload register-resident B with dec W_ih half (K cols 0..511)
#pragma unroll
    for (int nf = 0; nf < 2; ++nf)
#pragma unroll
        for (int sl = 0; sl < 16; ++sl)
            breg[nf][sl] = *reinterpret_cast<const s16x8*>(
                P.dWih + (size_t)ng[nf]*Hd + sl*32 + quad*8);

    float bias_d[2];
#pragma unroll
    for (int nf = 0; nf < 2; ++nf)
        bias_d[nf] = bf2f(P.dbih[ng[nf]]) + bf2f(P.dbhh[ng[nf]]);

    // attn row ids
    const int b0 = wg*4;
    const int s_uni = b0 >> 9;
    const int p0 = b0 & (Hd-1);

    // comb tile decode (waves 0-3 use r3 layout: 32 mt x 8 nt, tile 32m x 64n)
    const int cmt = wg & 31, cnt2 = wg >> 5;
    const int cbm0 = cmt << 5, cn0 = cnt2 << 6;
    const int cwm = (wave & 3) >> 1, cwn = wave & 1;
    const int carow = cbm0 + cwm*16 + l15;
    int ncol[2]; float bias_c[2], wxv_c[2][4];
#pragma unroll
    for (int j = 0; j < 2; ++j){
        ncol[j] = cn0 + cwn*32 + j*16 + l15;
        bias_c[j] = bf2f(P.cb[ncol[j]]);
        const s16x4 t4 = *reinterpret_cast<const s16x4*>(P.cW + (size_t)ncol[j]*(Hd+Din));
#pragma unroll
        for (int d = 0; d < 4; ++d) wxv_c[j][d] = bfbits2f(t4[d]);
    }

    for (int t = 0; t < Tlen; ++t){
        const int p = t & 1;

        // ---- D1: pred(t-1) + attention + context ----
        {
            const int j = tid;  // 512 threads cover j=0..511
            const float4 hv4 = *reinterpret_cast<const float4*>(
                P.hf32 + (size_t)(2*j + s_uni)*Hd + p0);
            hr_s[0][j] = hv4.x; hr_s[1][j] = hv4.y;
            hr_s[2][j] = hv4.z; hr_s[3][j] = hv4.w;
        }
        __syncthreads();

        if (wave < 4){
            const int b = b0 + wave;
            float x0, x1, x2, x3;
            if (t == 0){
                const bf16* xp = P.input + ((size_t)b*Lseq + (Lseq-1))*Din;
                x0 = bf2f(xp[0]); x1 = bf2f(xp[1]); x2 = bf2f(xp[2]); x3 = bf2f(xp[3]);
            } else {
                float q0=0.f, q1=0.f, q2=0.f, q3=0.f;
                const float* hb = P.hf32 + (size_t)b*Hd;
                for (int k = lane; k < Hd; k += 64){
                    const float hv = hb[k];
                    q0 += hv*bf2f(P.oW[k]);
                    q1 += hv*bf2f(P.oW[Hd+k]);
                    q2 += hv*bf2f(P.oW[2*Hd+k]);
                    q3 += hv*bf2f(P.oW[3*Hd+k]);
                }
#pragma unroll
                for (int off = 32; off; off >>= 1){
                    q0 += __shfl_down(q0, off); q1 += __shfl_down(q1, off);
                    q2 += __shfl_down(q2, off); q3 += __shfl_down(q3, off);
                }
                x0 = __shfl(q0,0) + bf2f(P.ob[0]);
                x1 = __shfl(q1,0) + bf2f(P.ob[1]);
                x2 = __shfl(q2,0) + bf2f(P.ob[2]);
                x3 = __shfl(q3,0) + bf2f(P.ob[3]);
                if (lane == 0){
                    const size_t o = ((size_t)b*Tlen + (t-1))*Din;
                    if (f32out){
                        float* dp = (float*)P.dout + o;
                        dp[0]=x0; dp[1]=x1; dp[2]=x2; dp[3]=x3;
                    } else {
                        bf16* dp = (bf16*)P.dout + o;
                        dp[0]=f2bf(x0); dp[1]=f2bf(x1); dp[2]=f2bf(x2); dp[3]=f2bf(x3);
                    }
                }
            }
            if (lane == 0){
                bf16* xp = P.xdec + (size_t)b*Din;
                xp[0]=f2bf(x0); xp[1]=f2bf(x1); xp[2]=f2bf(x2); xp[3]=f2bf(x3);
            }

            // logits + softmax
            float logit = -3.0e38f;
            if (lane < Lseq){
                float a0 = bf2f(P.ab[lane]);
                {
                    const bf16* wx = P.aW + (size_t)lane*(Hd+Din);
                    a0 += x0*bf2f(wx[0]) + x1*bf2f(wx[1]) + x2*bf2f(wx[2]) + x3*bf2f(wx[3]);
                }
                float a1 = 0.f, a2 = 0.f, a3 = 0.f;
                const bf16* wr = P.attnWr + (size_t)lane*Hd;
                for (int j = 0; j < Hd; j += 16){
                    float t4[4] = {0.f,0.f,0.f,0.f};
#pragma unroll
                    for (int q = 0; q < 4; ++q){
                        const float4 hv = *reinterpret_cast<const float4*>(&hr_s[wave][j + q*4]);
                        const s16x4 wv = *reinterpret_cast<const s16x4*>(wr + j + q*4);
                        t4[q] = hv.x*bfbits2f(wv[0]) + hv.y*bfbits2f(wv[1])
                              + hv.z*bfbits2f(wv[2]) + hv.w*bfbits2f(wv[3]);
                    }
                    a0 += t4[0]; a1 += t4[1]; a2 += t4[2]; a3 += t4[3];
                }
                logit = (a0 + a1) + (a2 + a3);
            }
            float mx = logit;
#pragma unroll
            for (int off = 32; off; off >>= 1) mx = fmaxf(mx, __shfl_xor(mx, off));
            const float e = (lane < Lseq) ? __expf(logit - mx) : 0.0f;
            float se = e;
#pragma unroll
            for (int off = 32; off; off >>= 1) se += __shfl_xor(se, off);
            if (lane < 64) aw_s[wave][lane] = e / se;
        }
        __syncthreads();

        // context: wave pair (r, r+4) splits l-range for row b0+r
        {
            const int r = wave & 3, half = wave >> 2;
            const int b = b0 + r;
            float acc8[8] = {0.f,0.f,0.f,0.f,0.f,0.f,0.f,0.f};
            const bf16* eb = P.encout + (size_t)b*Lseq*Hd + lane*8;
            for (int i = 0; i < 25; ++i){
                const int l = half*25 + i;
                const float w = aw_s[r][l];
                const s16x8 ch = *reinterpret_cast<const s16x8*>(eb + (size_t)l*Hd);
#pragma unroll
                for (int q = 0; q < 8; ++q) acc8[q] += w * bfbits2f(ch[q]);
            }
            float* cp = &ctx_s[half][r][lane*8];
            *reinterpret_cast<float4*>(cp)     = make_float4(acc8[0],acc8[1],acc8[2],acc8[3]);
            *reinterpret_cast<float4*>(cp + 4) = make_float4(acc8[4],acc8[5],acc8[6],acc8[7]);
        }
        __syncthreads();

        if (wave < 4){
            const int b = b0 + wave;
            s16x8 ov;
#pragma unroll
            for (int q = 0; q < 8; ++q)
                ov[q] = f2bfbits(ctx_s[0][wave][lane*8+q] + ctx_s[1][wave][lane*8+q]);
            *reinterpret_cast<s16x8*>(P.attnap + (size_t)b*Hd + lane*8) = ov;
        }
        gridbar(P.cnt, (++bar)*NWG);

        // ---- D2: comb GEMM (waves 0-3) ----
        if (wave < 4){
            f32x4 cacc[2];
#pragma unroll
            for (int j = 0; j < 2; ++j) cacc[j] = (f32x4)0.0f;
            const bf16* Ab = P.attnap + (size_t)carow*Hd + quad*8;
#pragma unroll
            for (int kk = 0; kk < 16; ++kk){
                s16x8 bfr[2];
#pragma unroll
                for (int j = 0; j < 2; ++j)
                    bfr[j] = *reinterpret_cast<const s16x8*>(
                        P.combWr + (size_t)ncol[j]*Hd + kk*32 + quad*8);
                const s16x8 afr2 = *reinterpret_cast<const s16x8*>(Ab + kk*32);
#pragma unroll
                for (int j = 0; j < 2; ++j)
                    cacc[j] = __builtin_amdgcn_mfma_f32_16x16x32_bf16(
                        afr2, bfr[j], cacc[j], 0, 0, 0);
            }
            bf16* outp = bufs[p];
#pragma unroll
            for (int j = 0; j < 2; ++j){
#pragma unroll
                for (int r = 0; r < 4; ++r){
                    const int m = cbm0 + cwm*16 + quad*4 + r;
                    const s16x4 xt = *reinterpret_cast<const s16x4*>(P.xdec + (size_t)m*Din);
                    float v = cacc[j][r] + bias_c[j]
                            + bfbits2f(xt[0])*wxv_c[j][0] + bfbits2f(xt[1])*wxv_c[j][1]
                            + bfbits2f(xt[2])*wxv_c[j][2] + bfbits2f(xt[3])*wxv_c[j][3];
                    v = fmaxf(v, 0.0f);
                    outp[(size_t)m*1024 + ncol[j]] = f2bf(v);
                }
            }
        }
        gridbar(P.cnt, (++bar)*NWG);

        // ---- D3: dec gates ----
        {
            const bf16* Ain = bufs[p];
            bf16* hout = bufs[p^1] + Hd;
            f32x4 acc[2][2];
#pragma unroll
            for (int mf=0; mf<2; ++mf)
#pragma unroll
                for (int nf=0; nf<2; ++nf) acc[mf][nf] = (f32x4)0.0f;

            s16x8 afr[2], bfr[2];
            // K half 1: comb cols 0..511, W_ih from registers
#pragma unroll
            for (int sl = 0; sl < 16; ++sl){
#pragma unroll
                for (int mf = 0; mf < 2; ++mf)
                    afr[mf] = *reinterpret_cast<const s16x8*>(
                        Ain + (size_t)(arow0 + mf*16)*1024 + sl*32 + quad*8);
#pragma unroll
                for (int mf = 0; mf < 2; ++mf)
#pragma unroll
                    for (int nf = 0; nf < 2; ++nf)
                        acc[mf][nf] = __builtin_amdgcn_mfma_f32_16x16x32_bf16(
                            afr[mf], breg[nf][sl], acc[mf][nf], 0, 0, 0);
            }
            // K half 2: h cols 512..1023, W_hh streamed from L2
#pragma unroll
            for (int sl = 0; sl < 16; ++sl){
#pragma unroll
                for (int nf = 0; nf < 2; ++nf)
                    bfr[nf] = *reinterpret_cast<const s16x8*>(
                        P.dWhh + (size_t)ng[nf]*Hd + sl*32 + quad*8);
#pragma unroll
                for (int mf = 0; mf < 2; ++mf)
                    afr[mf] = *reinterpret_cast<const s16x8*>(
                        Ain + (size_t)(arow0 + mf*16)*1024 + Hd + sl*32 + quad*8);
#pragma unroll
                for (int mf = 0; mf < 2; ++mf)
#pragma unroll
                    for (int nf = 0; nf < 2; ++nf)
                        acc[mf][nf] = __builtin_amdgcn_mfma_f32_16x16x32_bf16(
                            afr[mf], bfr[nf], acc[mf][nf], 0, 0, 0);
            }

#pragma unroll
            for (int mf = 0; mf < 2; ++mf){
#pragma unroll
                for (int r = 0; r < 4; ++r){
                    const int m = bm0 + wm*32 + mf*16 + quad*4 + r;
#pragma unroll
                    for (int nf = 0; nf < 2; ++nf){
                        const int n_loc = wn*32 + nf*16 + l15;
                        float gv = acc[mf][nf][r] + bias_d[nf];
                        const float gi = __shfl(gv, lbase+0);
                        const float gf = __shfl(gv, lbase+1);
                        const float gg = __shfl(gv, lbase+2);
                        const float go = __shfl(gv, lbase+3);
                        if ((lane & 3) == 0){
                            const int hcol = hc0 + (n_loc >> 2);
                            const size_t ci = (size_t)m*Hd + hcol;
                            const float cn = sigm(gf)*P.cbuf[ci] + sigm(gi)*tanhf(gg);
                            P.cbuf[ci] = cn;
                            const float hv = sigm(go)*tanhf(cn);
                            hout[(size_t)m*1024 + hcol] = f2bf(hv);
                            P.hf32[ci] = hv;
                        }
                    }
                }
            }
        }
        gridbar(P.cnt, (++bar)*NWG);
    }

    // ---- final pred (t = T-1) ----
    if (wave < 4){
        const int b = b0 + wave;
        float q0=0.f, q1=0.f, q2=0.f, q3=0.f;
        const float* hb = P.hf32 + (size_t)b*Hd;
        for (int k = lane; k < Hd; k += 64){
            const float hv = hb[k];
            q0 += hv*bf2f(P.oW[k]);
            q1 += hv*bf2f(P.oW[Hd+k]);
            q2 += hv*bf2f(P.oW[2*Hd+k]);
            q3 += hv*bf2f(P.oW[3*Hd+k]);
        }
#pragma unroll
        for (int off = 32; off; off >>= 1){
            q0 += __shfl_down(q0, off); q1 += __shfl_down(q1, off);
            q2 += __shfl_down(q2, off); q3 += __shfl_down(q3, off);
        }
        if (lane == 0){
            const size_t o = ((size_t)b*Tlen + (Tlen-1))*Din;
            const float r0 = q0 + bf2f(P.ob[0]), r1 = q1 + bf2f(P.ob[1]);
            const float r2 = q2 + bf2f(P.ob[2]), r3 = q3 + bf2f(P.ob[3]);
            if (f32out){
                float* dp = (float*)P.dout + o;
                dp[0]=r0; dp[1]=r1; dp[2]=r2; dp[3]=r3;
            } else {
                bf16* dp = (bf16*)P.dout + o;
                dp[0]=f2bf(r0); dp[1]=f2bf(r1); dp[2]=f2bf(r2); dp[3]=f2bf(r3);
            }
        }
    }
}

extern "C" void kernel_launch(void* const* d_in, const int* in_sizes, int n_in,
                              void* d_out, int out_size, void* d_ws, size_t ws_size,
                              hipStream_t stream)
{
    char* ws = (char*)d_ws;
    bf16*  Abuf0   = (bf16*)(ws + OFF_ABUF0);
    bf16*  Abuf1   = (bf16*)(ws + OFF_ABUF1);
    float* cbuf    = (float*)(ws + OFF_CBUF);
    float* hf32    = (float*)(ws + OFF_HF32);
    bf16*  attnap  = (bf16*)(ws + OFF_ATTNAP);
    bf16*  xdec    = (bf16*)(ws + OFF_XDEC);
    int*   flag    = (int*)(ws + OFF_FLAG);
    int*   cnt     = (int*)(ws + OFF_CNT);
    bf16*  combWr  = (bf16*)(ws + OFF_COMBWR);
    bf16*  attnWr  = (bf16*)(ws + OFF_ATTNWR);
    bf16*  wc      = (bf16*)(ws + OFF_WCACHE);
    bf16*  enc_out = (bf16*)(ws + OFF_ENCOUT);

    hipMemsetAsync(cnt, 0, 64, stream);

    probe_kernel<<<1, 256, 0, stream>>>((const unsigned int*)d_in[3], flag);

    Ptrs15 srcs;
    srcs.p[0]=d_in[0];  srcs.p[1]=d_in[2];  srcs.p[2]=d_in[3];  srcs.p[3]=d_in[4];
    srcs.p[4]=d_in[5];  srcs.p[5]=d_in[6];  srcs.p[6]=d_in[7];  srcs.p[7]=d_in[8];
    srcs.p[8]=d_in[9];  srcs.p[9]=d_in[10]; srcs.p[10]=d_in[11];srcs.p[11]=d_in[12];
    srcs.p[12]=d_in[13];srcs.p[13]=d_in[14];srcs.p[14]=d_in[15];
    convert_kernel<<<1024, 256, 0, stream>>>(srcs, flag, wc);

    setup_kernel<<<2048, 256, 0, stream>>>(Abuf0, Abuf1, cbuf, combWr, attnWr,
                                           wc+WC_CW, wc+WC_AW);

    MegaP P;
    P.input = wc+WC_INPUT; P.eWih = wc+WC_EWIH; P.eWhh = wc+WC_EWHH;
    P.ebih = wc+WC_EBIH;   P.ebhh = wc+WC_EBHH;
    P.aW = wc+WC_AW;  P.ab = wc+WC_AB;  P.cW = wc+WC_CW;  P.cb = wc+WC_CB;
    P.dWih = wc+WC_DWIH; P.dWhh = wc+WC_DWHH; P.dbih = wc+WC_DBIH; P.dbhh = wc+WC_DBHH;
    P.oW = wc+WC_OW;  P.ob = wc+WC_OB;
    P.combWr = combWr; P.attnWr = attnWr;
    P.A0 = Abuf0; P.A1 = Abuf1; P.encout = enc_out; P.attnap = attnap; P.xdec = xdec;
    P.cbuf = cbuf; P.hf32 = hf32; P.cnt = cnt; P.flag = flag; P.dout = d_out;

    mega_kernel<<<NWG, 512, 0, stream>>>(P);
}

// Round 7
// 3614.286 us; speedup vs baseline: 1.7646x; 1.7646x over previous
//
#include <hip/hip_runtime.h>
#include <hip/hip_bf16.h>

#define Bsz   1024
#define Lseq  50
#define Din   4
#define Hd    512
#define Tlen  30
#define NWG   256

typedef __hip_bfloat16 bf16;
typedef short s16x8 __attribute__((ext_vector_type(8)));
typedef short s16x4 __attribute__((ext_vector_type(4)));
typedef float f32x4 __attribute__((ext_vector_type(4)));

__device__ __forceinline__ float bf2f(bf16 x){ return __bfloat162float(x); }
__device__ __forceinline__ bf16  f2bf(float x){ return __float2bfloat16(x); }
__device__ __forceinline__ float bfbits2f(short u){
    union { unsigned int ui; float f; } v;
    v.ui = ((unsigned int)(unsigned short)u) << 16;
    return v.f;
}
__device__ __forceinline__ short f2bfbits(float x){
    bf16 h = f2bf(x); short s; __builtin_memcpy(&s, &h, 2); return s;
}
__device__ __forceinline__ float sigm(float x){ return 1.0f/(1.0f + __expf(-x)); }

// ---------------- ws layout (bytes) ----------------
#define OFF_ABUF0   (0u)
#define OFF_ABUF1   (2u<<20)
#define OFF_ATTNAP  (8u<<20)
#define OFF_XDEC    (9u<<20)
#define OFF_FLAG    ((9u<<20) + (16u<<10))
#define OFF_CNT     ((9u<<20) + (20u<<10))
#define OFF_COMBWR  ((9u<<20) + (32u<<10))
#define OFF_ATTNWR  ((9u<<20) + (600u<<10))
#define OFF_WCACHE  (10u<<20)
#define OFF_ENCOUT  (18u<<20)

// wcache element offsets (bf16 elements), 8-elem aligned per array
#define WC_INPUT 0
#define WC_EWIH  204800
#define WC_EWHH  212992
#define WC_EBIH  1261568
#define WC_EBHH  1263616
#define WC_AW    1265664
#define WC_AB    1291464
#define WC_CW    1291520
#define WC_CB    1555712
#define WC_DWIH  1556224
#define WC_DWHH  2604800
#define WC_DBIH  3653376
#define WC_DBHH  3655424
#define WC_OW    3657472
#define WC_OB    3659520
#define WC_TOTAL 3659524

__device__ __constant__ int WOFF[15] = {
    WC_INPUT, WC_EWIH, WC_EWHH, WC_EBIH, WC_EBHH, WC_AW, WC_AB, WC_CW,
    WC_CB, WC_DWIH, WC_DWHH, WC_DBIH, WC_DBHH, WC_OW, WC_OB };
__device__ __constant__ int WNUM[15] = {
    204800, 8192, 1048576, 2048, 2048, 25800, 50, 264192,
    512, 1048576, 1048576, 2048, 2048, 2048, 4 };

struct Ptrs15 { const void* p[15]; };

__global__ void probe_kernel(const unsigned int* __restrict__ w, int* flag){
    __shared__ int cnt;
    if (threadIdx.x == 0) cnt = 0;
    __syncthreads();
    int c = 0;
    for (int i = threadIdx.x; i < 4096; i += 256){
        unsigned e = (w[i] >> 7) & 0xFFu;
        c += (e >= 0x80u) ? 1 : 0;
    }
    atomicAdd(&cnt, c);
    __syncthreads();
    if (threadIdx.x == 0) *flag = (cnt > 400) ? 1 : 0;
}

__global__ __launch_bounds__(256) void convert_kernel(
    Ptrs15 srcs, const int* __restrict__ flag, bf16* __restrict__ dst)
{
    const int f = *flag;
    for (int idx = blockIdx.x*256 + threadIdx.x; idx < WC_TOTAL;
         idx += gridDim.x*256){
        int a = 0;
#pragma unroll
        for (int j = 1; j < 15; ++j) if (idx >= WOFF[j]) a = j;
        const int local = idx - WOFF[a];
        if (local >= WNUM[a]) continue;
        bf16 v;
        if (f) v = f2bf(((const float*)srcs.p[a])[local]);
        else   v = ((const bf16*)srcs.p[a])[local];
        dst[idx] = v;
    }
}

__global__ __launch_bounds__(256) void setup_kernel(
    bf16* __restrict__ Abuf0, bf16* __restrict__ Abuf1,
    bf16* __restrict__ combWr, bf16* __restrict__ attnWr,
    const bf16* __restrict__ cWc, const bf16* __restrict__ aWc)
{
    const unsigned idx = blockIdx.x*256u + threadIdx.x;
    if (idx < (unsigned)Bsz*Hd){
        const unsigned row = idx >> 9, col = idx & (Hd-1);
        const bf16 z = f2bf(0.0f);
        Abuf0[(size_t)row*1024 + Hd + col] = z;
        Abuf1[(size_t)row*1024 + Hd + col] = z;
    }
    if (idx < (unsigned)Hd*Hd)
        combWr[idx] = cWc[(size_t)(idx >> 9)*(Hd+Din) + Din + (idx & (Hd-1))];
    if (idx < (unsigned)Lseq*Hd)
        attnWr[idx] = aWc[(size_t)(idx >> 9)*(Hd+Din) + Din + (idx & (Hd-1))];
}

struct MegaP {
    const bf16 *input, *eWih, *eWhh, *ebih, *ebhh;
    const bf16 *aW, *ab, *cW, *cb, *dWih, *dWhh, *dbih, *dbhh, *oW, *ob;
    const bf16 *combWr, *attnWr;
    bf16 *A0, *A1, *encout, *attnap, *xdec;
    int *cntg, *cntl, *xccmap;
    const int *flag;
    void *dout;
};

// ---------------------------------------------------------------------------
// Persistent megakernel, XCD-local scheduling.
// 256 WGs x 512 thr, 1 WG/CU (159.7KB LDS). Each physical XCD (discovered
// via HW_REG_XCC_ID) owns 128 batch rows; its 32 WGs = 2 m-tiles x 16 n-tiles.
// Encoder: XCD-local barriers only (atomic + L1-only buffer_inv; L2 stays
// warm; W_hh register-resident). Decoder: 1 global barrier/step (h_r gather),
// local barriers for attn->comb->gates; dec W_ih in regs, dec W_hh in LDS.
// Fallback to global barriers if WG->XCD mapping isn't 32-balanced.
// R7 FIX: independent epoch counters for local vs global barriers (R6 kept
// them in lockstep -> LBAR waited for increments that could never arrive).
// ---------------------------------------------------------------------------
__global__ __launch_bounds__(512, 2) void mega_kernel(MegaP P)
{
    __shared__ short whh_lds[128*520];   // 133,120 B  dec W_hh slice (padded)
    __shared__ float hr_s[4][Hd];        // 8 KB
    __shared__ float ctx_s[2][4][Hd];    // 16 KB
    __shared__ float aw_s[4][64];        // 1 KB
    __shared__ int   xmap_s[NWG];        // 1 KB
    __shared__ int   info_s[4];

    const int wg = blockIdx.x, tid = threadIdx.x;
    const int wave = tid >> 6, lane = tid & 63;
    const int quad = lane >> 4, l15 = lane & 15;
    const int lbase = lane & ~3;
    const int f32out = *P.flag;

    int epg = 0;    // global barrier epochs (GBAR only)
    int eplc = 0;   // local barrier epochs (LBAR balanced path only)

    // ---- XCD discovery ----
    if (tid == 0){
        int xcc = 0;
        asm volatile("s_getreg_b32 %0, hwreg(HW_REG_XCC_ID)" : "=s"(xcc));
        P.xccmap[wg] = xcc & 7;
    }

    auto GBAR = [&](){
        ++epg;
        __syncthreads();
        if (tid == 0){
            __threadfence();
            __hip_atomic_fetch_add(P.cntg, 1, __ATOMIC_RELEASE, __HIP_MEMORY_SCOPE_AGENT);
            while (__hip_atomic_load(P.cntg, __ATOMIC_RELAXED, __HIP_MEMORY_SCOPE_AGENT) < epg*NWG)
                __builtin_amdgcn_s_sleep(1);
            (void)__hip_atomic_load(P.cntg, __ATOMIC_ACQUIRE, __HIP_MEMORY_SCOPE_AGENT);
        }
        __syncthreads();
    };

    GBAR();  // publish xccmap

    if (tid < NWG) xmap_s[tid] = P.xccmap[tid];
    __syncthreads();
    if (tid == 0){
        int cnt8[8] = {0,0,0,0,0,0,0,0};
        const int myx = xmap_s[wg];
        int rank = 0;
        for (int i = 0; i < NWG; ++i){
            cnt8[xmap_s[i]]++;
            if (i < wg && xmap_s[i] == myx) rank++;
        }
        int bal = 1;
        for (int i = 0; i < 8; ++i) bal &= (cnt8[i] == 32);
        info_s[0] = bal ? myx  : (wg >> 5);
        info_s[1] = bal ? rank : (wg & 31);
        info_s[2] = bal;
    }
    __syncthreads();
    const int xcd = info_s[0], slot = info_s[1], bal = info_s[2];

    int* cntl = P.cntl + xcd*16;   // own 64B line per XCD
    auto LBAR = [&](){
        if (!bal){ GBAR(); return; }
        ++eplc;
        __syncthreads();
        if (tid == 0){
            atomicAdd(cntl, 1);
            while (__hip_atomic_load(cntl, __ATOMIC_RELAXED, __HIP_MEMORY_SCOPE_AGENT) < eplc*32)
                __builtin_amdgcn_s_sleep(1);
        }
        __syncthreads();
        asm volatile("buffer_inv" ::: "memory");   // L1-only: L2 stays warm
    };

    bf16* bufs[2] = { P.A0, P.A1 };

    // ---- gates tiling from (xcd, slot) ----
    const int mtl = slot >> 4, ntl = slot & 15;
    const int bm0 = xcd*128 + mtl*64, hc0 = ntl*32;
    const int wm = wave >> 2, wn = wave & 3;
    const int arow0 = bm0 + wm*32 + l15;

    int ng[2];
#pragma unroll
    for (int nf = 0; nf < 2; ++nf){
        const int n = wn*32 + nf*16 + l15;
        ng[nf] = (n & 3)*Hd + hc0 + (n >> 2);
    }

    // ================= ENCODER =================
    float bias_e[2], wxv_e[2][4];
#pragma unroll
    for (int nf = 0; nf < 2; ++nf){
        bias_e[nf] = bf2f(P.ebih[ng[nf]]) + bf2f(P.ebhh[ng[nf]]);
        const s16x4 t4 = *reinterpret_cast<const s16x4*>(P.eWih + (size_t)ng[nf]*Din);
#pragma unroll
        for (int d = 0; d < 4; ++d) wxv_e[nf][d] = bfbits2f(t4[d]);
    }

    s16x8 breg[2][16];
#pragma unroll
    for (int nf = 0; nf < 2; ++nf)
#pragma unroll
        for (int sl = 0; sl < 16; ++sl)
            breg[nf][sl] = *reinterpret_cast<const s16x8*>(
                P.eWhh + (size_t)ng[nf]*Hd + sl*32 + quad*8);

    float creg[2][2][4];
#pragma unroll
    for (int a = 0; a < 2; ++a)
#pragma unroll
        for (int b = 0; b < 2; ++b)
#pragma unroll
            for (int r = 0; r < 4; ++r) creg[a][b][r] = 0.0f;

    for (int t = 0; t < Lseq; ++t){
        const bf16* Ain = bufs[t&1] + Hd;
        bf16* hout = bufs[(t+1)&1] + Hd;

        f32x4 acc[2][2];
#pragma unroll
        for (int mf=0; mf<2; ++mf)
#pragma unroll
            for (int nf=0; nf<2; ++nf) acc[mf][nf] = (f32x4)0.0f;

        s16x8 afr[2];
#pragma unroll
        for (int sl = 0; sl < 16; ++sl){
#pragma unroll
            for (int mf = 0; mf < 2; ++mf)
                afr[mf] = *reinterpret_cast<const s16x8*>(
                    Ain + (size_t)(arow0 + mf*16)*1024 + sl*32 + quad*8);
#pragma unroll
            for (int mf = 0; mf < 2; ++mf)
#pragma unroll
                for (int nf = 0; nf < 2; ++nf)
                    acc[mf][nf] = __builtin_amdgcn_mfma_f32_16x16x32_bf16(
                        afr[mf], breg[nf][sl], acc[mf][nf], 0, 0, 0);
        }

#pragma unroll
        for (int mf = 0; mf < 2; ++mf){
#pragma unroll
            for (int r = 0; r < 4; ++r){
                const int m = bm0 + wm*32 + mf*16 + quad*4 + r;
                const s16x4 xt = *reinterpret_cast<const s16x4*>(
                    P.input + ((size_t)m*Lseq + t)*Din);
                float xv[4];
#pragma unroll
                for (int d = 0; d < 4; ++d) xv[d] = bfbits2f(xt[d]);
#pragma unroll
                for (int nf = 0; nf < 2; ++nf){
                    const int n_loc = wn*32 + nf*16 + l15;
                    float gv = acc[mf][nf][r] + bias_e[nf]
                             + xv[0]*wxv_e[nf][0] + xv[1]*wxv_e[nf][1]
                             + xv[2]*wxv_e[nf][2] + xv[3]*wxv_e[nf][3];
                    const float gi = __shfl(gv, lbase+0);
                    const float gf = __shfl(gv, lbase+1);
                    const float gg = __shfl(gv, lbase+2);
                    const float go = __shfl(gv, lbase+3);
                    if ((lane & 3) == 0){
                        const int hcol = hc0 + (n_loc >> 2);
                        const float cn = sigm(gf)*creg[mf][nf][r] + sigm(gi)*tanhf(gg);
                        creg[mf][nf][r] = cn;
                        const float hv = sigm(go)*tanhf(cn);
                        const bf16 hb = f2bf(hv);
                        hout[(size_t)m*1024 + hcol] = hb;
                        P.encout[((size_t)m*Lseq + t)*Hd + hcol] = hb;
                    }
                }
            }
        }
        if (t == Lseq-1) GBAR(); else LBAR();
    }

    // ================= DECODER =================
#pragma unroll
    for (int nf = 0; nf < 2; ++nf)
#pragma unroll
        for (int sl = 0; sl < 16; ++sl)
            breg[nf][sl] = *reinterpret_cast<const s16x8*>(
                P.dWih + (size_t)ng[nf]*Hd + sl*32 + quad*8);

    float bias_d[2];
#pragma unroll
    for (int nf = 0; nf < 2; ++nf)
        bias_d[nf] = bf2f(P.dbih[ng[nf]]) + bf2f(P.dbhh[ng[nf]]);

    // dec W_hh slice -> LDS (persists across all 30 steps)
    for (int i = tid; i < 128*64; i += 512){
        const int col = i >> 6;               // 0..127 local gate col
        const int k8  = (i & 63) * 8;
        const int g   = (col & 3)*Hd + hc0 + (col >> 2);
        const s16x8 v = *reinterpret_cast<const s16x8*>(P.dWhh + (size_t)g*Hd + k8);
        *reinterpret_cast<s16x8*>(&whh_lds[col*520 + k8]) = v;
    }

    // attn rows
    const int b0 = xcd*128 + slot*4;
    const int s_uni = b0 >> 9;
    const int p0 = b0 & (Hd-1);

    // comb tile: rows bm0..+64, cols hc0..+32 (same XCD rows/cols as gates)
    const int cwm = wave >> 1, cwn = wave & 1;
    const int ccol = hc0 + cwn*16 + l15;
    float bias_c, wxv_c[4];
    {
        bias_c = bf2f(P.cb[ccol]);
        const s16x4 t4 = *reinterpret_cast<const s16x4*>(P.cW + (size_t)ccol*(Hd+Din));
#pragma unroll
        for (int d = 0; d < 4; ++d) wxv_c[d] = bfbits2f(t4[d]);
    }
    __syncthreads();  // whh_lds fill complete

    for (int t = 0; t < Tlen; ++t){
        const int p = t & 1;
        const bf16* hprev = bufs[p] + Hd;    // h_{t-1}, ld 1024

        // ---- D1: hr staging + pred(t-1) + attention + context ----
        {
            const s16x4 hv = *reinterpret_cast<const s16x4*>(
                hprev + (size_t)(2*tid + s_uni)*1024 + p0);
            hr_s[0][tid] = bfbits2f(hv[0]);
            hr_s[1][tid] = bfbits2f(hv[1]);
            hr_s[2][tid] = bfbits2f(hv[2]);
            hr_s[3][tid] = bfbits2f(hv[3]);
        }
        __syncthreads();

        if (wave < 4){
            const int b = b0 + wave;
            float x0, x1, x2, x3;
            if (t == 0){
                const bf16* xp = P.input + ((size_t)b*Lseq + (Lseq-1))*Din;
                x0 = bf2f(xp[0]); x1 = bf2f(xp[1]); x2 = bf2f(xp[2]); x3 = bf2f(xp[3]);
            } else {
                float q0=0.f, q1=0.f, q2=0.f, q3=0.f;
                const bf16* hb = hprev + (size_t)b*1024;
                for (int k = lane; k < Hd; k += 64){
                    const float hv = bf2f(hb[k]);
                    q0 += hv*bf2f(P.oW[k]);
                    q1 += hv*bf2f(P.oW[Hd+k]);
                    q2 += hv*bf2f(P.oW[2*Hd+k]);
                    q3 += hv*bf2f(P.oW[3*Hd+k]);
                }
#pragma unroll
                for (int off = 32; off; off >>= 1){
                    q0 += __shfl_down(q0, off); q1 += __shfl_down(q1, off);
                    q2 += __shfl_down(q2, off); q3 += __shfl_down(q3, off);
                }
                x0 = __shfl(q0,0) + bf2f(P.ob[0]);
                x1 = __shfl(q1,0) + bf2f(P.ob[1]);
                x2 = __shfl(q2,0) + bf2f(P.ob[2]);
                x3 = __shfl(q3,0) + bf2f(P.ob[3]);
                if (lane == 0){
                    const size_t o = ((size_t)b*Tlen + (t-1))*Din;
                    if (f32out){
                        float* dp = (float*)P.dout + o;
                        dp[0]=x0; dp[1]=x1; dp[2]=x2; dp[3]=x3;
                    } else {
                        bf16* dp = (bf16*)P.dout + o;
                        dp[0]=f2bf(x0); dp[1]=f2bf(x1); dp[2]=f2bf(x2); dp[3]=f2bf(x3);
                    }
                }
            }
            if (lane == 0){
                bf16* xp = P.xdec + (size_t)b*Din;
                xp[0]=f2bf(x0); xp[1]=f2bf(x1); xp[2]=f2bf(x2); xp[3]=f2bf(x3);
            }

            float logit = -3.0e38f;
            if (lane < Lseq){
                float a0 = bf2f(P.ab[lane]);
                {
                    const bf16* wx = P.aW + (size_t)lane*(Hd+Din);
                    a0 += x0*bf2f(wx[0]) + x1*bf2f(wx[1]) + x2*bf2f(wx[2]) + x3*bf2f(wx[3]);
                }
                float a1 = 0.f, a2 = 0.f, a3 = 0.f;
                const bf16* wr = P.attnWr + (size_t)lane*Hd;
                for (int j = 0; j < Hd; j += 16){
                    float t4[4] = {0.f,0.f,0.f,0.f};
#pragma unroll
                    for (int q = 0; q < 4; ++q){
                        const float4 hv = *reinterpret_cast<const float4*>(&hr_s[wave][j + q*4]);
                        const s16x4 wv = *reinterpret_cast<const s16x4*>(wr + j + q*4);
                        t4[q] = hv.x*bfbits2f(wv[0]) + hv.y*bfbits2f(wv[1])
                              + hv.z*bfbits2f(wv[2]) + hv.w*bfbits2f(wv[3]);
                    }
                    a0 += t4[0]; a1 += t4[1]; a2 += t4[2]; a3 += t4[3];
                }
                logit = (a0 + a1) + (a2 + a3);
            }
            float mx = logit;
#pragma unroll
            for (int off = 32; off; off >>= 1) mx = fmaxf(mx, __shfl_xor(mx, off));
            const float e = (lane < Lseq) ? __expf(logit - mx) : 0.0f;
            float se = e;
#pragma unroll
            for (int off = 32; off; off >>= 1) se += __shfl_xor(se, off);
            aw_s[wave][lane] = e / se;
        }
        __syncthreads();

        {
            const int r = wave & 3, half = wave >> 2;
            const int b = b0 + r;
            float acc8[8] = {0.f,0.f,0.f,0.f,0.f,0.f,0.f,0.f};
            const bf16* eb = P.encout + (size_t)b*Lseq*Hd + lane*8;
            for (int i = 0; i < 25; ++i){
                const int l = half*25 + i;
                const float w = aw_s[r][l];
                const s16x8 ch = *reinterpret_cast<const s16x8*>(eb + (size_t)l*Hd);
#pragma unroll
                for (int q = 0; q < 8; ++q) acc8[q] += w * bfbits2f(ch[q]);
            }
            float* cp = &ctx_s[half][r][lane*8];
            *reinterpret_cast<float4*>(cp)     = make_float4(acc8[0],acc8[1],acc8[2],acc8[3]);
            *reinterpret_cast<float4*>(cp + 4) = make_float4(acc8[4],acc8[5],acc8[6],acc8[7]);
        }
        __syncthreads();

        if (wave < 4){
            const int b = b0 + wave;
            s16x8 ov;
#pragma unroll
            for (int q = 0; q < 8; ++q)
                ov[q] = f2bfbits(ctx_s[0][wave][lane*8+q] + ctx_s[1][wave][lane*8+q]);
            *reinterpret_cast<s16x8*>(P.attnap + (size_t)b*Hd + lane*8) = ov;
        }
        LBAR();

        // ---- D2: comb GEMM -> bufs[p] cols 0..511 (rows-local) ----
        {
            f32x4 cacc = (f32x4)0.0f;
            const bf16* Ab = P.attnap + (size_t)(bm0 + cwm*16 + l15)*Hd + quad*8;
#pragma unroll
            for (int kk = 0; kk < 16; ++kk){
                const s16x8 bfr = *reinterpret_cast<const s16x8*>(
                    P.combWr + (size_t)ccol*Hd + kk*32 + quad*8);
                const s16x8 afr2 = *reinterpret_cast<const s16x8*>(Ab + kk*32);
                cacc = __builtin_amdgcn_mfma_f32_16x16x32_bf16(afr2, bfr, cacc, 0, 0, 0);
            }
            bf16* outp = bufs[p];
#pragma unroll
            for (int r = 0; r < 4; ++r){
                const int m = bm0 + cwm*16 + quad*4 + r;
                const s16x4 xt = *reinterpret_cast<const s16x4*>(P.xdec + (size_t)m*Din);
                float v = cacc[r] + bias_c
                        + bfbits2f(xt[0])*wxv_c[0] + bfbits2f(xt[1])*wxv_c[1]
                        + bfbits2f(xt[2])*wxv_c[2] + bfbits2f(xt[3])*wxv_c[3];
                v = fmaxf(v, 0.0f);
                outp[(size_t)m*1024 + ccol] = f2bf(v);
            }
        }
        LBAR();

        // ---- D3: dec gates ----
        {
            const bf16* Ain = bufs[p];
            bf16* hout = bufs[p^1] + Hd;
            f32x4 acc[2][2];
#pragma unroll
            for (int mf=0; mf<2; ++mf)
#pragma unroll
                for (int nf=0; nf<2; ++nf) acc[mf][nf] = (f32x4)0.0f;

            s16x8 afr[2], bfr[2];
            // K half 1: comb cols (W_ih in regs)
#pragma unroll
            for (int sl = 0; sl < 16; ++sl){
#pragma unroll
                for (int mf = 0; mf < 2; ++mf)
                    afr[mf] = *reinterpret_cast<const s16x8*>(
                        Ain + (size_t)(arow0 + mf*16)*1024 + sl*32 + quad*8);
#pragma unroll
                for (int mf = 0; mf < 2; ++mf)
#pragma unroll
                    for (int nf = 0; nf < 2; ++nf)
                        acc[mf][nf] = __builtin_amdgcn_mfma_f32_16x16x32_bf16(
                            afr[mf], breg[nf][sl], acc[mf][nf], 0, 0, 0);
            }
            // K half 2: h cols (W_hh from LDS)
#pragma unroll
            for (int sl = 0; sl < 16; ++sl){
#pragma unroll
                for (int nf = 0; nf < 2; ++nf){
                    const int nl = wn*32 + nf*16 + l15;
                    bfr[nf] = *reinterpret_cast<const s16x8*>(
                        &whh_lds[nl*520 + sl*32 + quad*8]);
                }
#pragma unroll
                for (int mf = 0; mf < 2; ++mf)
                    afr[mf] = *reinterpret_cast<const s16x8*>(
                        Ain + (size_t)(arow0 + mf*16)*1024 + Hd + sl*32 + quad*8);
#pragma unroll
                for (int mf = 0; mf < 2; ++mf)
#pragma unroll
                    for (int nf = 0; nf < 2; ++nf)
                        acc[mf][nf] = __builtin_amdgcn_mfma_f32_16x16x32_bf16(
                            afr[mf], bfr[nf], acc[mf][nf], 0, 0, 0);
            }

#pragma unroll
            for (int mf = 0; mf < 2; ++mf){
#pragma unroll
                for (int r = 0; r < 4; ++r){
                    const int m = bm0 + wm*32 + mf*16 + quad*4 + r;
#pragma unroll
                    for (int nf = 0; nf < 2; ++nf){
                        const int n_loc = wn*32 + nf*16 + l15;
                        float gv = acc[mf][nf][r] + bias_d[nf];
                        const float gi = __shfl(gv, lbase+0);
                        const float gf = __shfl(gv, lbase+1);
                        const float gg = __shfl(gv, lbase+2);
                        const float go = __shfl(gv, lbase+3);
                        if ((lane & 3) == 0){
                            const int hcol = hc0 + (n_loc >> 2);
                            const float cn = sigm(gf)*creg[mf][nf][r] + sigm(gi)*tanhf(gg);
                            creg[mf][nf][r] = cn;
                            const float hv = sigm(go)*tanhf(cn);
                            hout[(size_t)m*1024 + hcol] = f2bf(hv);
                        }
                    }
                }
            }
        }
        GBAR();
    }

    // ---- final pred (t = T-1), rows-local ----
    if (wave < 4){
        const int b = b0 + wave;
        const bf16* hb = bufs[Tlen & 1] + Hd + (size_t)b*1024;
        float q0=0.f, q1=0.f, q2=0.f, q3=0.f;
        for (int k = lane; k < Hd; k += 64){
            const float hv = bf2f(hb[k]);
            q0 += hv*bf2f(P.oW[k]);
            q1 += hv*bf2f(P.oW[Hd+k]);
            q2 += hv*bf2f(P.oW[2*Hd+k]);
            q3 += hv*bf2f(P.oW[3*Hd+k]);
        }
#pragma unroll
        for (int off = 32; off; off >>= 1){
            q0 += __shfl_down(q0, off); q1 += __shfl_down(q1, off);
            q2 += __shfl_down(q2, off); q3 += __shfl_down(q3, off);
        }
        if (lane == 0){
            const size_t o = ((size_t)b*Tlen + (Tlen-1))*Din;
            const float r0 = q0 + bf2f(P.ob[0]), r1 = q1 + bf2f(P.ob[1]);
            const float r2 = q2 + bf2f(P.ob[2]), r3 = q3 + bf2f(P.ob[3]);
            if (f32out){
                float* dp = (float*)P.dout + o;
                dp[0]=r0; dp[1]=r1; dp[2]=r2; dp[3]=r3;
            } else {
                bf16* dp = (bf16*)P.dout + o;
                dp[0]=f2bf(r0); dp[1]=f2bf(r1); dp[2]=f2bf(r2); dp[3]=f2bf(r3);
            }
        }
    }
}

extern "C" void kernel_launch(void* const* d_in, const int* in_sizes, int n_in,
                              void* d_out, int out_size, void* d_ws, size_t ws_size,
                              hipStream_t stream)
{
    char* ws = (char*)d_ws;
    bf16*  Abuf0   = (bf16*)(ws + OFF_ABUF0);
    bf16*  Abuf1   = (bf16*)(ws + OFF_ABUF1);
    bf16*  attnap  = (bf16*)(ws + OFF_ATTNAP);
    bf16*  xdec    = (bf16*)(ws + OFF_XDEC);
    int*   flag    = (int*)(ws + OFF_FLAG);
    int*   cntblk  = (int*)(ws + OFF_CNT);
    bf16*  combWr  = (bf16*)(ws + OFF_COMBWR);
    bf16*  attnWr  = (bf16*)(ws + OFF_ATTNWR);
    bf16*  wc      = (bf16*)(ws + OFF_WCACHE);
    bf16*  enc_out = (bf16*)(ws + OFF_ENCOUT);

    hipMemsetAsync(cntblk, 0, 4096, stream);

    probe_kernel<<<1, 256, 0, stream>>>((const unsigned int*)d_in[3], flag);

    Ptrs15 srcs;
    srcs.p[0]=d_in[0];  srcs.p[1]=d_in[2];  srcs.p[2]=d_in[3];  srcs.p[3]=d_in[4];
    srcs.p[4]=d_in[5];  srcs.p[5]=d_in[6];  srcs.p[6]=d_in[7];  srcs.p[7]=d_in[8];
    srcs.p[8]=d_in[9];  srcs.p[9]=d_in[10]; srcs.p[10]=d_in[11];srcs.p[11]=d_in[12];
    srcs.p[12]=d_in[13];srcs.p[13]=d_in[14];srcs.p[14]=d_in[15];
    convert_kernel<<<1024, 256, 0, stream>>>(srcs, flag, wc);

    setup_kernel<<<2048, 256, 0, stream>>>(Abuf0, Abuf1, combWr, attnWr,
                                           wc+WC_CW, wc+WC_AW);

    MegaP P;
    P.input = wc+WC_INPUT; P.eWih = wc+WC_EWIH; P.eWhh = wc+WC_EWHH;
    P.ebih = wc+WC_EBIH;   P.ebhh = wc+WC_EBHH;
    P.aW = wc+WC_AW;  P.ab = wc+WC_AB;  P.cW = wc+WC_CW;  P.cb = wc+WC_CB;
    P.dWih = wc+WC_DWIH; P.dWhh = wc+WC_DWHH; P.dbih = wc+WC_DBIH; P.dbhh = wc+WC_DBHH;
    P.oW = wc+WC_OW;  P.ob = wc+WC_OB;
    P.combWr = combWr; P.attnWr = attnWr;
    P.A0 = Abuf0; P.A1 = Abuf1; P.encout = enc_out; P.attnap = attnap; P.xdec = xdec;
    P.cntg = cntblk; P.cntl = cntblk + 16; P.xccmap = cntblk + 16 + 8*16;
    P.flag = flag; P.dout = d_out;

    mega_kernel<<<NWG, 512, 0, stream>>>(P);
}